// Round 3
// baseline (478.580 us; speedup 1.0000x reference)
//
#include <hip/hip_runtime.h>
#include <hip/hip_bf16.h>

#define B_ 4
#define N_ 256
#define D_ 256
#define KG_ 128
#define EPS_ 1e-5f

typedef __bf16 bf16x8 __attribute__((ext_vector_type(8)));
typedef __bf16 bf16x4 __attribute__((ext_vector_type(4)));
typedef float  f32x4v __attribute__((ext_vector_type(4)));

__device__ __forceinline__ void gload16(const void* g, void* l) {
    __builtin_amdgcn_global_load_lds(
        (const __attribute__((address_space(1))) uint32_t*)g,
        (__attribute__((address_space(3))) uint32_t*)l, 16, 0, 0);
}

// ---------------------------------------------------------------------------
// S1: W_kcT[d][g] = sum_k W_kg[g][k] * Wc[k][d]   (bf16, transposed)
//     bias_tot[d] = sum_k b_kg[k] * Wc[k][d] + b1l[d]
// ---------------------------------------------------------------------------
__global__ __launch_bounds__(256) void s1_kernel(
    const float* __restrict__ Wkg, const float* __restrict__ W1l,
    const float* __restrict__ bkg, const float* __restrict__ b1l,
    __bf16* __restrict__ WkcT, float* __restrict__ biastot)
{
    const int d = threadIdx.x;
    if (blockIdx.x == KG_) {
        float acc = 0.f;
        for (int k = 0; k < D_; ++k)
            acc += bkg[k] * W1l[(2 * D_ + k) * D_ + d];
        biastot[d] = acc + b1l[d];
        return;
    }
    const int g = blockIdx.x;
    float acc = 0.f;
    for (int k = 0; k < D_; ++k)
        acc += Wkg[g * D_ + k] * W1l[(2 * D_ + k) * D_ + d];
    WkcT[d * KG_ + g] = (__bf16)acc;
}

// ---------------------------------------------------------------------------
// S2: a_pb[row][d] = (h @ Wa)[row][d] + bias_tot[d]   (fp32)
//     bb  [row][d] = (h @ Wb)[row][d]                  (bf16)
// ---------------------------------------------------------------------------
__global__ __launch_bounds__(256) void s2_kernel(
    const float* __restrict__ hin, const float* __restrict__ W1l,
    const float* __restrict__ biastot,
    float* __restrict__ apb, __bf16* __restrict__ bbout)
{
    __shared__ float hT[D_][4];
    const int tid = threadIdx.x;
    const int R = blockIdx.x * 4;
    {
        const int r = tid & 3, c4 = (tid >> 2) << 2;
        const float4 v = *(const float4*)(hin + (R + r) * D_ + c4);
        hT[c4 + 0][r] = v.x; hT[c4 + 1][r] = v.y;
        hT[c4 + 2][r] = v.z; hT[c4 + 3][r] = v.w;
    }
    __syncthreads();
    float aa[4] = {0.f, 0.f, 0.f, 0.f};
    float ab[4] = {0.f, 0.f, 0.f, 0.f};
#pragma unroll 4
    for (int e = 0; e < D_; ++e) {
        const float wa = W1l[e * D_ + tid];
        const float wb = W1l[(D_ + e) * D_ + tid];
        const float4 hv = *(const float4*)&hT[e][0];
        aa[0] += hv.x * wa; aa[1] += hv.y * wa; aa[2] += hv.z * wa; aa[3] += hv.w * wa;
        ab[0] += hv.x * wb; ab[1] += hv.y * wb; ab[2] += hv.z * wb; ab[3] += hv.w * wb;
    }
    const float bt = biastot[tid];
#pragma unroll
    for (int r = 0; r < 4; ++r) {
        apb[(R + r) * D_ + tid]    = aa[r] + bt;
        bbout[(R + r) * D_ + tid]  = (__bf16)ab[r];
    }
}

// ---------------------------------------------------------------------------
// BIG: one block per (b,i). Counted-vmcnt raw-barrier pipeline:
//   E tile: depth-3 register prefetch (global f32 -> reg, cvt -> swizzled LDS)
//   B tile: global_load_lds (source pre-swizzled), completion via vmcnt(2)/(0)
//   MFMA operand-swapped: D[d][j]; lane holds 4 consecutive d for one j.
// ---------------------------------------------------------------------------
__global__ __launch_bounds__(256, 3) void big_kernel(
    const float* __restrict__ rel, const int* __restrict__ adj,
    const __bf16* __restrict__ WkcT, const float* __restrict__ apb,
    const __bf16* __restrict__ bb, const float* __restrict__ W2l,
    const float* __restrict__ b2l, const float* __restrict__ hin,
    const float* __restrict__ gmm, const float* __restrict__ bta,
    float* __restrict__ hout)
{
    __shared__ __align__(16) __bf16 Et[2][16 * KG_];   // 4 KB each
    __shared__ __align__(16) __bf16 Bt[2][16 * D_];    // 8 KB each
    __shared__ float adjL[N_];
    __shared__ float rL[D_];
    __shared__ float red[8];
    __shared__ float sdeg;

    const int tid = threadIdx.x;
    const int lane = tid & 63;
    const int w = tid >> 6;
    const int l15 = lane & 15;
    const int lg = lane >> 4;     // 0..3
    const int bi = blockIdx.x;    // b*256 + i
    const int dw = w * 64;

    const float*  Ebase  = rel + (size_t)bi * N_ * KG_;
    const __bf16* bbBase = bb + (size_t)(bi >> 8) * N_ * D_;

    // persistent Wkc fragments (A-operand): lane l15 = d-row, regs = k
    bf16x8 wf[4][4];
#pragma unroll
    for (int nb = 0; nb < 4; ++nb)
#pragma unroll
        for (int kk = 0; kk < 4; ++kk)
            wf[nb][kk] = *(const bf16x8*)(WkcT + (dw + nb * 16 + l15) * KG_ + kk * 32 + lg * 8);

    // apb for this lane's d-quad: d = dw + nb*16 + lg*4 + q
    f32x4v apbv[4];
#pragma unroll
    for (int nb = 0; nb < 4; ++nb)
        apbv[nb] = *(const f32x4v*)(apb + bi * D_ + dw + nb * 16 + lg * 4);

    adjL[tid] = (float)adj[bi * N_ + tid];

    // ---- staging helpers ----
    const int jp = tid >> 4;          // E row 0..15
    const int k0 = (tid & 15) * 8;    // E k-offset
    const float* esrc = Ebase + jp * KG_ + k0;

    f32x4v e0a, e0b, e1a, e1b, e2a, e2b;   // 3 prefetch sets

    auto eload = [&](int t, f32x4v& a, f32x4v& b) {
        const float* s = esrc + t * 16 * KG_;
        a = *(const f32x4v*)s;
        b = *(const f32x4v*)(s + 4);
    };
    auto ewrite = [&](int buf, const f32x4v& a, const f32x4v& b) {
        bf16x8 v;
        v[0] = (__bf16)a[0]; v[1] = (__bf16)a[1]; v[2] = (__bf16)a[2]; v[3] = (__bf16)a[3];
        v[4] = (__bf16)b[0]; v[5] = (__bf16)b[1]; v[6] = (__bf16)b[2]; v[7] = (__bf16)b[3];
        int off = jp * 256 + k0 * 2;
        off ^= (jp & 7) << 4;
        *(bf16x8*)((char*)&Et[buf][0] + off) = v;
    };
    // B tile: LDS unit u (16B) holds global unit (u&~31)|((u&31)^(row&7)), row=u>>5
    auto bstage = [&](int t, int buf) {
        const __bf16* Gb = bbBase + t * 16 * D_;
        char* ldsbase = (char*)&Bt[buf][0] + (tid & 0xC0) * 16;
#pragma unroll
        for (int i = 0; i < 2; ++i) {
            const int u = tid + i * 256;
            const int gu = (u & ~31) | ((u & 31) ^ ((u >> 5) & 7));
            gload16(Gb + gu * 8, ldsbase + i * 256 * 16);
        }
    };

    float racc[4][4] = {};

    auto compute = [&](int jb, int buf) {
        bf16x8 af[4];
#pragma unroll
        for (int kk = 0; kk < 4; ++kk) {
            int off = l15 * 256 + kk * 64 + lg * 16;
            off ^= (l15 & 7) << 4;
            af[kk] = *(const bf16x8*)((const char*)&Et[buf][0] + off);
        }
        f32x4v acc[4];
#pragma unroll
        for (int nb = 0; nb < 4; ++nb) acc[nb] = (f32x4v){0.f, 0.f, 0.f, 0.f};
#pragma unroll
        for (int kk = 0; kk < 4; ++kk)
#pragma unroll
            for (int nb = 0; nb < 4; ++nb)
                acc[nb] = __builtin_amdgcn_mfma_f32_16x16x32_bf16(wf[nb][kk], af[kk], acc[nb], 0, 0, 0);

        const float adjj = adjL[jb * 16 + l15];   // lane's j = l15
#pragma unroll
        for (int nb = 0; nb < 4; ++nb) {
            const int dbyte = (dw + nb * 16 + lg * 4) * 2;
            const int u = (l15 << 5) | ((dbyte >> 4) ^ (l15 & 7));
            const bf16x4 bv = *(const bf16x4*)((const char*)&Bt[buf][0] + u * 16 + (dbyte & 15));
#pragma unroll
            for (int q = 0; q < 4; ++q) {
                float t = acc[nb][q] + apbv[nb][q] + (float)bv[q];
                t = fmaxf(t, 0.f);
                racc[nb][q] += t * adjj;
            }
        }
    };

    // ---- prologue: stage tile0, prefetch tiles 1,2 ----
    bstage(0, 0);
    __builtin_amdgcn_sched_barrier(0);
    eload(0, e0a, e0b); eload(1, e1a, e1b); eload(2, e2a, e2b);
    ewrite(0, e0a, e0b);
    asm volatile("s_waitcnt vmcnt(0) lgkmcnt(0)" ::: "memory");
    __builtin_amdgcn_s_barrier();
    __builtin_amdgcn_sched_barrier(0);

#pragma unroll
    for (int jb = 0; jb < 16; ++jb) {
        const int buf = jb & 1;
        if (jb < 15) {
            const int sw = (jb + 1) % 3;          // set holding tile jb+1
            if (sw == 0)      ewrite(buf ^ 1, e0a, e0b);
            else if (sw == 1) ewrite(buf ^ 1, e1a, e1b);
            else              ewrite(buf ^ 1, e2a, e2b);
            bstage(jb + 1, buf ^ 1);
            __builtin_amdgcn_sched_barrier(0);     // pin B-loads before E-loads
        }
        if (jb < 13) {
            const int sl = jb % 3;                 // free set gets tile jb+3
            if (sl == 0)      eload(jb + 3, e0a, e0b);
            else if (sl == 1) eload(jb + 3, e1a, e1b);
            else              eload(jb + 3, e2a, e2b);
        }
        compute(jb, buf);
        if (jb < 13) {
            asm volatile("s_waitcnt vmcnt(2) lgkmcnt(0)" ::: "memory");
            __builtin_amdgcn_s_barrier();
            __builtin_amdgcn_sched_barrier(0);
        } else if (jb < 15) {
            asm volatile("s_waitcnt vmcnt(0) lgkmcnt(0)" ::: "memory");
            __builtin_amdgcn_s_barrier();
            __builtin_amdgcn_sched_barrier(0);
        }
    }

    // ---- reduce racc over the 16 l15-lanes (j) -> rL[d] ----
#pragma unroll
    for (int nb = 0; nb < 4; ++nb) {
        float v0 = racc[nb][0], v1 = racc[nb][1], v2 = racc[nb][2], v3 = racc[nb][3];
#pragma unroll
        for (int off = 1; off <= 8; off <<= 1) {
            v0 += __shfl_xor(v0, off, 64);
            v1 += __shfl_xor(v1, off, 64);
            v2 += __shfl_xor(v2, off, 64);
            v3 += __shfl_xor(v3, off, 64);
        }
        if (l15 == 0) {
            float4 o; o.x = v0; o.y = v1; o.z = v2; o.w = v3;
            *(float4*)&rL[dw + nb * 16 + lg * 4] = o;
        }
    }
    if (w == 0) {
        float s = adjL[lane] + adjL[lane + 64] + adjL[lane + 128] + adjL[lane + 192];
#pragma unroll
        for (int off = 32; off >= 1; off >>= 1) s += __shfl_xor(s, off, 64);
        if (lane == 0) sdeg = s;
    }
    __syncthreads();

    // ---- msg = r @ W2 (fp32), residual, LayerNorm ----
    const int d = tid;
    float m0 = 0.f, m1 = 0.f, m2 = 0.f, m3 = 0.f;
    for (int e = 0; e < D_; e += 4) {
        const float4 rv = *(const float4*)&rL[e];
        m0 += rv.x * W2l[(e + 0) * D_ + d];
        m1 += rv.y * W2l[(e + 1) * D_ + d];
        m2 += rv.z * W2l[(e + 2) * D_ + d];
        m3 += rv.w * W2l[(e + 3) * D_ + d];
    }
    const float t = hin[bi * D_ + d] + (m0 + m1) + (m2 + m3) + sdeg * b2l[d];

    float s = t, sq = t * t;
#pragma unroll
    for (int off = 32; off >= 1; off >>= 1) {
        s  += __shfl_xor(s, off, 64);
        sq += __shfl_xor(sq, off, 64);
    }
    if (lane == 0) { red[w] = s; red[4 + w] = sq; }
    __syncthreads();
    const float S  = red[0] + red[1] + red[2] + red[3];
    const float SQ = red[4] + red[5] + red[6] + red[7];
    const float mu = S * (1.f / D_);
    const float var = SQ * (1.f / D_) - mu * mu;
    const float rstd = rsqrtf(var + EPS_);
    hout[bi * D_ + d] = (t - mu) * rstd * gmm[d] + bta[d];
}

// ---------------------------------------------------------------------------
extern "C" void kernel_launch(void* const* d_in, const int* in_sizes, int n_in,
                              void* d_out, int out_size, void* d_ws, size_t ws_size,
                              hipStream_t stream)
{
    const float* node  = (const float*)d_in[0];
    const float* rel   = (const float*)d_in[1];
    const int*   adj   = (const int*)d_in[2];
    const float* Wkg   = (const float*)d_in[3];
    const float* bkg   = (const float*)d_in[4];
    const float* W1    = (const float*)d_in[5];
    const float* b1    = (const float*)d_in[6];
    const float* W2    = (const float*)d_in[7];
    const float* b2    = (const float*)d_in[8];
    const float* gamma = (const float*)d_in[9];
    const float* beta  = (const float*)d_in[10];
    float* out = (float*)d_out;

    char* ws = (char*)d_ws;
    float*  h1    = (float*)(ws);                       // 1 MB
    float*  apb   = (float*)(ws + (1 << 20));           // 1 MB
    __bf16* bbuf  = (__bf16*)(ws + (2 << 20));          // 512 KB
    float*  bias  = (float*)(ws + (3 << 20));           // 1 KB
    __bf16* WkcT  = (__bf16*)(ws + (3 << 20) + 4096);   // 64 KB

    for (int l = 0; l < 2; ++l) {
        const float* W1l = W1 + (size_t)l * 3 * D_ * D_;
        const float* hin = (l == 0) ? node : h1;
        float* hout = (l == 1) ? out : h1;

        s1_kernel<<<KG_ + 1, 256, 0, stream>>>(Wkg, W1l, bkg, b1 + l * D_, WkcT, bias);
        s2_kernel<<<(B_ * N_) / 4, 256, 0, stream>>>(hin, W1l, bias, apb, bbuf);
        big_kernel<<<B_ * N_, 256, 0, stream>>>(rel, adj, WkcT, apb, bbuf,
                                                W2 + (size_t)l * D_ * D_, b2 + l * D_,
                                                hin, gamma, beta, hout);
    }
}

// Round 4
// 234.458 us; speedup vs baseline: 2.0412x; 2.0412x over previous
//
#include <hip/hip_runtime.h>
#include <hip/hip_bf16.h>

#define B_ 4
#define N_ 256
#define D_ 256
#define KG_ 128
#define EPS_ 1e-5f

typedef __bf16 bf16x8 __attribute__((ext_vector_type(8)));
typedef __bf16 bf16x4 __attribute__((ext_vector_type(4)));
typedef float  f32x4v __attribute__((ext_vector_type(4)));

__device__ __forceinline__ void gload16(const void* g, void* l) {
    __builtin_amdgcn_global_load_lds(
        (const __attribute__((address_space(1))) uint32_t*)g,
        (__attribute__((address_space(3))) uint32_t*)l, 16, 0, 0);
}

// ---------------------------------------------------------------------------
// S1: W_kcT[d][g] = sum_k W_kg[g][k] * Wc[k][d]   (bf16, transposed)
//     bias_tot[d] = sum_k b_kg[k] * Wc[k][d] + b1l[d]
// ---------------------------------------------------------------------------
__global__ __launch_bounds__(256) void s1_kernel(
    const float* __restrict__ Wkg, const float* __restrict__ W1l,
    const float* __restrict__ bkg, const float* __restrict__ b1l,
    __bf16* __restrict__ WkcT, float* __restrict__ biastot)
{
    const int d = threadIdx.x;
    if (blockIdx.x == KG_) {
        float acc = 0.f;
        for (int k = 0; k < D_; ++k)
            acc += bkg[k] * W1l[(2 * D_ + k) * D_ + d];
        biastot[d] = acc + b1l[d];
        return;
    }
    const int g = blockIdx.x;
    float acc = 0.f;
    for (int k = 0; k < D_; ++k)
        acc += Wkg[g * D_ + k] * W1l[(2 * D_ + k) * D_ + d];
    WkcT[d * KG_ + g] = (__bf16)acc;
}

// ---------------------------------------------------------------------------
// S2: a_pb[row][d] = (h @ Wa)[row][d] + bias_tot[d]   (fp32)
//     bb  [row][d] = (h @ Wb)[row][d]                  (bf16)
// ---------------------------------------------------------------------------
__global__ __launch_bounds__(256) void s2_kernel(
    const float* __restrict__ hin, const float* __restrict__ W1l,
    const float* __restrict__ biastot,
    float* __restrict__ apb, __bf16* __restrict__ bbout)
{
    __shared__ float hT[D_][4];
    const int tid = threadIdx.x;
    const int R = blockIdx.x * 4;
    {
        const int r = tid & 3, c4 = (tid >> 2) << 2;
        const float4 v = *(const float4*)(hin + (R + r) * D_ + c4);
        hT[c4 + 0][r] = v.x; hT[c4 + 1][r] = v.y;
        hT[c4 + 2][r] = v.z; hT[c4 + 3][r] = v.w;
    }
    __syncthreads();
    float aa[4] = {0.f, 0.f, 0.f, 0.f};
    float ab[4] = {0.f, 0.f, 0.f, 0.f};
#pragma unroll 4
    for (int e = 0; e < D_; ++e) {
        const float wa = W1l[e * D_ + tid];
        const float wb = W1l[(D_ + e) * D_ + tid];
        const float4 hv = *(const float4*)&hT[e][0];
        aa[0] += hv.x * wa; aa[1] += hv.y * wa; aa[2] += hv.z * wa; aa[3] += hv.w * wa;
        ab[0] += hv.x * wb; ab[1] += hv.y * wb; ab[2] += hv.z * wb; ab[3] += hv.w * wb;
    }
    const float bt = biastot[tid];
#pragma unroll
    for (int r = 0; r < 4; ++r) {
        apb[(R + r) * D_ + tid]    = aa[r] + bt;
        bbout[(R + r) * D_ + tid]  = (__bf16)ab[r];
    }
}

// ---------------------------------------------------------------------------
// BIG: one block per (b,i). Quad-buffered gload_lds pipeline, counted vmcnt.
//   E tile: raw f32 (8 KB), XOR-source-swizzled; cvt to bf16 at fragment read.
//   B tile: bf16 (8 KB), same swizzle.
//   MFMA operand-swapped: D[d][j]; lane (l15=j, lg) holds d-quad per nb.
// ---------------------------------------------------------------------------
__global__ __launch_bounds__(256) void big_kernel(
    const float* __restrict__ rel, const int* __restrict__ adj,
    const __bf16* __restrict__ WkcT, const float* __restrict__ apb,
    const __bf16* __restrict__ bb, const float* __restrict__ W2l,
    const float* __restrict__ b2l, const float* __restrict__ hin,
    const float* __restrict__ gmm, const float* __restrict__ bta,
    float* __restrict__ hout)
{
    __shared__ __align__(16) float  Et[4][16 * KG_];   // 8 KB each (f32)
    __shared__ __align__(16) __bf16 Bt[4][16 * D_];    // 8 KB each
    __shared__ float adjL[N_];
    __shared__ float rL[D_];
    __shared__ float red[8];
    __shared__ float sdeg;

    const int tid = threadIdx.x;
    const int lane = tid & 63;
    const int w = tid >> 6;
    const int l15 = lane & 15;
    const int lg = lane >> 4;     // 0..3
    const int bi = blockIdx.x;    // b*256 + i
    const int dw = w * 64;
    const int p = l15 & 7;        // read-side XOR key

    const float*  Ebase  = rel + (size_t)bi * N_ * KG_;
    const __bf16* bbBase = bb + (size_t)(bi >> 8) * N_ * D_;

    // persistent Wkc fragments (A-operand): lane l15 = d-row, regs = k
    bf16x8 wf[4][4];
#pragma unroll
    for (int nb = 0; nb < 4; ++nb)
#pragma unroll
        for (int kk = 0; kk < 4; ++kk)
            wf[nb][kk] = *(const bf16x8*)(WkcT + (dw + nb * 16 + l15) * KG_ + kk * 32 + lg * 8);

    f32x4v apbv[4];   // d = dw + nb*16 + lg*4 + q
#pragma unroll
    for (int nb = 0; nb < 4; ++nb)
        apbv[nb] = *(const f32x4v*)(apb + bi * D_ + dw + nb * 16 + lg * 4);

    adjL[tid] = (float)adj[bi * N_ + tid];
    __builtin_amdgcn_sched_barrier(0);

    // staging: 512 16B-units per tile; thread t stages LDS units {t, t+256}.
    // LDS unit u holds global unit (u&~31)|((u&31)^((u>>5)&7))  (row = u>>5).
    auto stageE = [&](int t, int buf) {
        const char* Gb = (const char*)(Ebase + t * 16 * KG_);
        char* ldsw = (char*)&Et[buf][0] + (tid & 192) * 16;
#pragma unroll
        for (int i = 0; i < 2; ++i) {
            const int u = tid + i * 256;
            const int gu = (u & ~31) | ((u & 31) ^ ((u >> 5) & 7));
            gload16(Gb + gu * 16, ldsw + i * 4096);
        }
    };
    auto stageB = [&](int t, int buf) {
        const char* Gb = (const char*)(bbBase + t * 16 * D_);
        char* ldsw = (char*)&Bt[buf][0] + (tid & 192) * 16;
#pragma unroll
        for (int i = 0; i < 2; ++i) {
            const int u = tid + i * 256;
            const int gu = (u & ~31) | ((u & 31) ^ ((u >> 5) & 7));
            gload16(Gb + gu * 16, ldsw + i * 4096);
        }
    };

    float racc[4][4] = {};

    auto compute = [&](int jb, int buf) {
        bf16x8 af[4];
#pragma unroll
        for (int kk = 0; kk < 4; ++kk) {
            const int u0 = (kk * 8 + lg * 2) ^ p;
            const int u1 = (kk * 8 + lg * 2 + 1) ^ p;
            const f32x4v fa = *(const f32x4v*)((const char*)&Et[buf][0] + l15 * 512 + u0 * 16);
            const f32x4v fb = *(const f32x4v*)((const char*)&Et[buf][0] + l15 * 512 + u1 * 16);
            bf16x8 v;
            v[0] = (__bf16)fa[0]; v[1] = (__bf16)fa[1]; v[2] = (__bf16)fa[2]; v[3] = (__bf16)fa[3];
            v[4] = (__bf16)fb[0]; v[5] = (__bf16)fb[1]; v[6] = (__bf16)fb[2]; v[7] = (__bf16)fb[3];
            af[kk] = v;
        }
        f32x4v acc[4];
#pragma unroll
        for (int nb = 0; nb < 4; ++nb) acc[nb] = (f32x4v){0.f, 0.f, 0.f, 0.f};
#pragma unroll
        for (int kk = 0; kk < 4; ++kk)
#pragma unroll
            for (int nb = 0; nb < 4; ++nb)
                acc[nb] = __builtin_amdgcn_mfma_f32_16x16x32_bf16(wf[nb][kk], af[kk], acc[nb], 0, 0, 0);

        const float adjj = adjL[jb * 16 + l15];   // lane's j = l15
#pragma unroll
        for (int nb = 0; nb < 4; ++nb) {
            const int dbyte = w * 128 + nb * 32 + lg * 8;
            const int u = (dbyte >> 4) ^ p;
            const bf16x4 bv = *(const bf16x4*)((const char*)&Bt[buf][0] + l15 * 512 + u * 16 + (dbyte & 15));
#pragma unroll
            for (int q = 0; q < 4; ++q) {
                float t = acc[nb][q] + apbv[nb][q] + (float)bv[q];
                t = fmaxf(t, 0.f);
                racc[nb][q] += t * adjj;
            }
        }
    };

    // ---- prologue: stage tiles 0,1,2 (12 gloads/wave in flight) ----
    stageE(0, 0); stageB(0, 0);
    stageE(1, 1); stageB(1, 1);
    stageE(2, 2); stageB(2, 2);
    __builtin_amdgcn_sched_barrier(0);
    asm volatile("s_waitcnt vmcnt(8) lgkmcnt(0)" ::: "memory");
    __builtin_amdgcn_s_barrier();
    __builtin_amdgcn_sched_barrier(0);

#pragma unroll
    for (int jb = 0; jb < 16; ++jb) {
        const int buf = jb & 3;
        if (jb < 13) {
            stageE(jb + 3, (jb + 3) & 3);
            stageB(jb + 3, (jb + 3) & 3);
            __builtin_amdgcn_sched_barrier(0);   // pin prefetch issue early
        }
        compute(jb, buf);
        if (jb < 13)      asm volatile("s_waitcnt vmcnt(8)" ::: "memory");
        else if (jb == 13) asm volatile("s_waitcnt vmcnt(4)" ::: "memory");
        else if (jb == 14) asm volatile("s_waitcnt vmcnt(0)" ::: "memory");
        if (jb < 15) {
            __builtin_amdgcn_s_barrier();
            __builtin_amdgcn_sched_barrier(0);
        }
    }

    // ---- reduce racc over the 16 l15-lanes (j) -> rL[d] ----
#pragma unroll
    for (int nb = 0; nb < 4; ++nb) {
        float v0 = racc[nb][0], v1 = racc[nb][1], v2 = racc[nb][2], v3 = racc[nb][3];
#pragma unroll
        for (int off = 1; off <= 8; off <<= 1) {
            v0 += __shfl_xor(v0, off, 64);
            v1 += __shfl_xor(v1, off, 64);
            v2 += __shfl_xor(v2, off, 64);
            v3 += __shfl_xor(v3, off, 64);
        }
        if (l15 == 0) {
            float4 o; o.x = v0; o.y = v1; o.z = v2; o.w = v3;
            *(float4*)&rL[dw + nb * 16 + lg * 4] = o;
        }
    }
    if (w == 0) {
        float s = adjL[lane] + adjL[lane + 64] + adjL[lane + 128] + adjL[lane + 192];
#pragma unroll
        for (int off = 32; off >= 1; off >>= 1) s += __shfl_xor(s, off, 64);
        if (lane == 0) sdeg = s;
    }
    __syncthreads();

    // ---- msg = r @ W2 (fp32), residual, LayerNorm ----
    const int d = tid;
    float m0 = 0.f, m1 = 0.f, m2 = 0.f, m3 = 0.f;
    for (int e = 0; e < D_; e += 4) {
        const float4 rv = *(const float4*)&rL[e];
        m0 += rv.x * W2l[(e + 0) * D_ + d];
        m1 += rv.y * W2l[(e + 1) * D_ + d];
        m2 += rv.z * W2l[(e + 2) * D_ + d];
        m3 += rv.w * W2l[(e + 3) * D_ + d];
    }
    const float t = hin[bi * D_ + d] + (m0 + m1) + (m2 + m3) + sdeg * b2l[d];

    float s = t, sq = t * t;
#pragma unroll
    for (int off = 32; off >= 1; off >>= 1) {
        s  += __shfl_xor(s, off, 64);
        sq += __shfl_xor(sq, off, 64);
    }
    if (lane == 0) { red[w] = s; red[4 + w] = sq; }
    __syncthreads();
    const float S  = red[0] + red[1] + red[2] + red[3];
    const float SQ = red[4] + red[5] + red[6] + red[7];
    const float mu = S * (1.f / D_);
    const float var = SQ * (1.f / D_) - mu * mu;
    const float rstd = rsqrtf(var + EPS_);
    hout[bi * D_ + d] = (t - mu) * rstd * gmm[d] + bta[d];
}

// ---------------------------------------------------------------------------
extern "C" void kernel_launch(void* const* d_in, const int* in_sizes, int n_in,
                              void* d_out, int out_size, void* d_ws, size_t ws_size,
                              hipStream_t stream)
{
    const float* node  = (const float*)d_in[0];
    const float* rel   = (const float*)d_in[1];
    const int*   adj   = (const int*)d_in[2];
    const float* Wkg   = (const float*)d_in[3];
    const float* bkg   = (const float*)d_in[4];
    const float* W1    = (const float*)d_in[5];
    const float* b1    = (const float*)d_in[6];
    const float* W2    = (const float*)d_in[7];
    const float* b2    = (const float*)d_in[8];
    const float* gamma = (const float*)d_in[9];
    const float* beta  = (const float*)d_in[10];
    float* out = (float*)d_out;

    char* ws = (char*)d_ws;
    float*  h1    = (float*)(ws);                       // 1 MB
    float*  apb   = (float*)(ws + (1 << 20));           // 1 MB
    __bf16* bbuf  = (__bf16*)(ws + (2 << 20));          // 512 KB
    float*  bias  = (float*)(ws + (3 << 20));           // 1 KB
    __bf16* WkcT  = (__bf16*)(ws + (3 << 20) + 4096);   // 64 KB

    for (int l = 0; l < 2; ++l) {
        const float* W1l = W1 + (size_t)l * 3 * D_ * D_;
        const float* hin = (l == 0) ? node : h1;
        float* hout = (l == 1) ? out : h1;

        s1_kernel<<<KG_ + 1, 256, 0, stream>>>(Wkg, W1l, bkg, b1 + l * D_, WkcT, bias);
        s2_kernel<<<(B_ * N_) / 4, 256, 0, stream>>>(hin, W1l, bias, apb, bbuf);
        big_kernel<<<B_ * N_, 256, 0, stream>>>(rel, adj, WkcT, apb, bbuf,
                                                W2 + (size_t)l * D_ * D_, b2 + l * D_,
                                                hin, gamma, beta, hout);
    }
}

// Round 5
// 178.396 us; speedup vs baseline: 2.6827x; 1.3143x over previous
//
#include <hip/hip_runtime.h>
#include <hip/hip_bf16.h>

#define B_ 4
#define N_ 256
#define D_ 256
#define KG_ 128
#define EPS_ 1e-5f

typedef __bf16 bf16x8 __attribute__((ext_vector_type(8)));
typedef __bf16 bf16x4 __attribute__((ext_vector_type(4)));
typedef float  f32x4v __attribute__((ext_vector_type(4)));

__device__ __forceinline__ void gload16(const void* g, void* l) {
    __builtin_amdgcn_global_load_lds(
        (const __attribute__((address_space(1))) uint32_t*)g,
        (__attribute__((address_space(3))) uint32_t*)l, 16, 0, 0);
}

// ---------------------------------------------------------------------------
// S1: W_kcT[d][g] = sum_k W_kg[g][k] * Wc[k][d]   (bf16, transposed)
//     bias_tot[d] = sum_k b_kg[k] * Wc[k][d] + b1l[d]
// ---------------------------------------------------------------------------
__global__ __launch_bounds__(256) void s1_kernel(
    const float* __restrict__ Wkg, const float* __restrict__ W1l,
    const float* __restrict__ bkg, const float* __restrict__ b1l,
    __bf16* __restrict__ WkcT, float* __restrict__ biastot)
{
    const int d = threadIdx.x;
    if (blockIdx.x == KG_) {
        float acc = 0.f;
        for (int k = 0; k < D_; ++k)
            acc += bkg[k] * W1l[(2 * D_ + k) * D_ + d];
        biastot[d] = acc + b1l[d];
        return;
    }
    const int g = blockIdx.x;
    float acc = 0.f;
    for (int k = 0; k < D_; ++k)
        acc += Wkg[g * D_ + k] * W1l[(2 * D_ + k) * D_ + d];
    WkcT[d * KG_ + g] = (__bf16)acc;
}

// ---------------------------------------------------------------------------
// S2: a_pb[row][d] = (h @ Wa)[row][d] + bias_tot[d]   (fp32)
//     bb  [row][d] = (h @ Wb)[row][d]                  (bf16)
// ---------------------------------------------------------------------------
__global__ __launch_bounds__(256) void s2_kernel(
    const float* __restrict__ hin, const float* __restrict__ W1l,
    const float* __restrict__ biastot,
    float* __restrict__ apb, __bf16* __restrict__ bbout)
{
    __shared__ float hT[D_][4];
    const int tid = threadIdx.x;
    const int R = blockIdx.x * 4;
    {
        const int r = tid & 3, c4 = (tid >> 2) << 2;
        const float4 v = *(const float4*)(hin + (R + r) * D_ + c4);
        hT[c4 + 0][r] = v.x; hT[c4 + 1][r] = v.y;
        hT[c4 + 2][r] = v.z; hT[c4 + 3][r] = v.w;
    }
    __syncthreads();
    float aa[4] = {0.f, 0.f, 0.f, 0.f};
    float ab[4] = {0.f, 0.f, 0.f, 0.f};
#pragma unroll 4
    for (int e = 0; e < D_; ++e) {
        const float wa = W1l[e * D_ + tid];
        const float wb = W1l[(D_ + e) * D_ + tid];
        const float4 hv = *(const float4*)&hT[e][0];
        aa[0] += hv.x * wa; aa[1] += hv.y * wa; aa[2] += hv.z * wa; aa[3] += hv.w * wa;
        ab[0] += hv.x * wb; ab[1] += hv.y * wb; ab[2] += hv.z * wb; ab[3] += hv.w * wb;
    }
    const float bt = biastot[tid];
#pragma unroll
    for (int r = 0; r < 4; ++r) {
        apb[(R + r) * D_ + tid]    = aa[r] + bt;
        bbout[(R + r) * D_ + tid]  = (__bf16)ab[r];
    }
}

// ---------------------------------------------------------------------------
// BIG: one block per (b,i). 4 bulk rounds (64 j each), single-buffered slabs:
//   Et: 64j x 128k bf16 (16 KB), reg-staged f32->bf16, XOR-swizzled rows.
//   Bt: 64j x 256d bf16 (32 KB), gload_lds with XOR source-swizzle.
// Per round: stage -> barrier -> 4 jj sub-tiles x {4 ds_read, 16 MFMA,
// relu-mask-accum epilogue} -> barrier.  TLP (3 blocks/CU) hides staging.
// MFMA operand-swapped: D[d][j]; lane (l15=j, lg,q = d-quad).
// ---------------------------------------------------------------------------
__global__ __launch_bounds__(256, 2) void big_kernel(
    const float* __restrict__ rel, const int* __restrict__ adj,
    const __bf16* __restrict__ WkcT, const float* __restrict__ apb,
    const __bf16* __restrict__ bb, const float* __restrict__ W2l,
    const float* __restrict__ b2l, const float* __restrict__ hin,
    const float* __restrict__ gmm, const float* __restrict__ bta,
    float* __restrict__ hout)
{
    __shared__ __align__(16) __bf16 Et[64 * KG_];   // 16 KB
    __shared__ __align__(16) __bf16 Bt[64 * D_];    // 32 KB
    __shared__ float adjL[N_];
    __shared__ float rL[D_];
    __shared__ float red[8];
    __shared__ float sdeg;

    const int tid = threadIdx.x;
    const int lane = tid & 63;
    const int w = tid >> 6;
    const int l15 = lane & 15;
    const int lg = lane >> 4;     // 0..3
    const int bi = blockIdx.x;    // b*256 + i
    const int dw = w * 64;

    const float*  Ebase  = rel + (size_t)bi * N_ * KG_;
    const __bf16* bbBase = bb + (size_t)(bi >> 8) * N_ * D_;

    // persistent Wkc fragments (A-operand): row(d)=l15, k=kk*32+lg*8
    bf16x8 wf[4][4];
#pragma unroll
    for (int nb = 0; nb < 4; ++nb)
#pragma unroll
        for (int kk = 0; kk < 4; ++kk)
            wf[nb][kk] = *(const bf16x8*)(WkcT + (dw + nb * 16 + l15) * KG_ + kk * 32 + lg * 8);

    f32x4v apbv[4];   // d = dw + nb*16 + lg*4 + q
#pragma unroll
    for (int nb = 0; nb < 4; ++nb)
        apbv[nb] = *(const f32x4v*)(apb + bi * D_ + dw + nb * 16 + lg * 4);

    adjL[tid] = (float)adj[bi * N_ + tid];

    float racc[4][4] = {};

    for (int jq = 0; jq < 4; ++jq) {
        // ---- stage Bt: 2048 16B-units; LDS unit u <- global unit
        //      (u&~31)|((u&31)^((u>>5)&7)), row = u>>5 (512 B rows) ----
        {
            const char* Gb = (const char*)(bbBase + jq * 64 * D_);
            char* ldsw = (char*)Bt + (tid & 192) * 16;
#pragma unroll
            for (int i = 0; i < 8; ++i) {
                const int u = tid + i * 256;
                const int gu = (u & ~31) | ((u & 31) ^ ((u >> 5) & 7));
                gload16(Gb + gu * 16, ldsw + i * 4096);
            }
        }
        // ---- stage Et: 1024 bf16x8-units; row = v>>4, k0 = (v&15)*8 ----
        {
#pragma unroll
            for (int rep = 0; rep < 4; ++rep) {
                const int v = tid + rep * 256;
                const int row = v >> 4;
                const int k0 = (v & 15) * 8;
                const float* s = Ebase + (jq * 64 + row) * KG_ + k0;
                const f32x4v fa = *(const f32x4v*)s;
                const f32x4v fb = *(const f32x4v*)(s + 4);
                bf16x8 v8;
                v8[0] = (__bf16)fa[0]; v8[1] = (__bf16)fa[1];
                v8[2] = (__bf16)fa[2]; v8[3] = (__bf16)fa[3];
                v8[4] = (__bf16)fb[0]; v8[5] = (__bf16)fb[1];
                v8[6] = (__bf16)fb[2]; v8[7] = (__bf16)fb[3];
                const int off = (row * 256 + k0 * 2) ^ ((row & 7) << 4);
                *(bf16x8*)((char*)Et + off) = v8;
            }
        }
        __syncthreads();   // drains vmcnt(0)+lgkmcnt(0): both slabs ready

        // ---- compute: 4 jj sub-tiles of 16 j ----
#pragma unroll
        for (int jj = 0; jj < 4; ++jj) {
            const int row = jj * 16 + l15;
            bf16x8 af[4];
#pragma unroll
            for (int kk = 0; kk < 4; ++kk) {
                const int off = (row * 256 + kk * 64 + lg * 16) ^ ((row & 7) << 4);
                af[kk] = *(const bf16x8*)((const char*)Et + off);
            }
            f32x4v acc[4];
#pragma unroll
            for (int nb = 0; nb < 4; ++nb) acc[nb] = (f32x4v){0.f, 0.f, 0.f, 0.f};
#pragma unroll
            for (int kk = 0; kk < 4; ++kk)
#pragma unroll
                for (int nb = 0; nb < 4; ++nb)
                    acc[nb] = __builtin_amdgcn_mfma_f32_16x16x32_bf16(wf[nb][kk], af[kk], acc[nb], 0, 0, 0);

            const float adjj = adjL[jq * 64 + row];
#pragma unroll
            for (int nb = 0; nb < 4; ++nb) {
                const int dbyte = w * 128 + nb * 32 + lg * 8;
                const int su = (dbyte >> 4) ^ (row & 7);
                const bf16x4 bv = *(const bf16x4*)((const char*)Bt + row * 512 + su * 16 + (dbyte & 15));
#pragma unroll
                for (int q = 0; q < 4; ++q) {
                    float t = acc[nb][q] + apbv[nb][q] + (float)bv[q];
                    t = fmaxf(t, 0.f);
                    racc[nb][q] += t * adjj;
                }
            }
        }
        __syncthreads();   // slabs free for next round
    }

    // ---- reduce racc over the 16 l15-lanes (j) -> rL[d] ----
#pragma unroll
    for (int nb = 0; nb < 4; ++nb) {
        float v0 = racc[nb][0], v1 = racc[nb][1], v2 = racc[nb][2], v3 = racc[nb][3];
#pragma unroll
        for (int off = 1; off <= 8; off <<= 1) {
            v0 += __shfl_xor(v0, off, 64);
            v1 += __shfl_xor(v1, off, 64);
            v2 += __shfl_xor(v2, off, 64);
            v3 += __shfl_xor(v3, off, 64);
        }
        if (l15 == 0) {
            float4 o; o.x = v0; o.y = v1; o.z = v2; o.w = v3;
            *(float4*)&rL[dw + nb * 16 + lg * 4] = o;
        }
    }
    if (w == 0) {
        float s = adjL[lane] + adjL[lane + 64] + adjL[lane + 128] + adjL[lane + 192];
#pragma unroll
        for (int off = 32; off >= 1; off >>= 1) s += __shfl_xor(s, off, 64);
        if (lane == 0) sdeg = s;
    }
    __syncthreads();

    // ---- msg = r @ W2 (fp32), residual, LayerNorm ----
    const int d = tid;
    float m0 = 0.f, m1 = 0.f, m2 = 0.f, m3 = 0.f;
    for (int e = 0; e < D_; e += 4) {
        const float4 rv = *(const float4*)&rL[e];
        m0 += rv.x * W2l[(e + 0) * D_ + d];
        m1 += rv.y * W2l[(e + 1) * D_ + d];
        m2 += rv.z * W2l[(e + 2) * D_ + d];
        m3 += rv.w * W2l[(e + 3) * D_ + d];
    }
    const float t = hin[bi * D_ + d] + (m0 + m1) + (m2 + m3) + sdeg * b2l[d];

    float s = t, sq = t * t;
#pragma unroll
    for (int off = 32; off >= 1; off >>= 1) {
        s  += __shfl_xor(s, off, 64);
        sq += __shfl_xor(sq, off, 64);
    }
    if (lane == 0) { red[w] = s; red[4 + w] = sq; }
    __syncthreads();
    const float S  = red[0] + red[1] + red[2] + red[3];
    const float SQ = red[4] + red[5] + red[6] + red[7];
    const float mu = S * (1.f / D_);
    const float var = SQ * (1.f / D_) - mu * mu;
    const float rstd = rsqrtf(var + EPS_);
    hout[bi * D_ + d] = (t - mu) * rstd * gmm[d] + bta[d];
}

// ---------------------------------------------------------------------------
extern "C" void kernel_launch(void* const* d_in, const int* in_sizes, int n_in,
                              void* d_out, int out_size, void* d_ws, size_t ws_size,
                              hipStream_t stream)
{
    const float* node  = (const float*)d_in[0];
    const float* rel   = (const float*)d_in[1];
    const int*   adj   = (const int*)d_in[2];
    const float* Wkg   = (const float*)d_in[3];
    const float* bkg   = (const float*)d_in[4];
    const float* W1    = (const float*)d_in[5];
    const float* b1    = (const float*)d_in[6];
    const float* W2    = (const float*)d_in[7];
    const float* b2    = (const float*)d_in[8];
    const float* gamma = (const float*)d_in[9];
    const float* beta  = (const float*)d_in[10];
    float* out = (float*)d_out;

    char* ws = (char*)d_ws;
    float*  h1    = (float*)(ws);                       // 1 MB
    float*  apb   = (float*)(ws + (1 << 20));           // 1 MB
    __bf16* bbuf  = (__bf16*)(ws + (2 << 20));          // 512 KB
    float*  bias  = (float*)(ws + (3 << 20));           // 1 KB
    __bf16* WkcT  = (__bf16*)(ws + (3 << 20) + 4096);   // 64 KB

    for (int l = 0; l < 2; ++l) {
        const float* W1l = W1 + (size_t)l * 3 * D_ * D_;
        const float* hin = (l == 0) ? node : h1;
        float* hout = (l == 1) ? out : h1;

        s1_kernel<<<KG_ + 1, 256, 0, stream>>>(Wkg, W1l, bkg, b1 + l * D_, WkcT, bias);
        s2_kernel<<<(B_ * N_) / 4, 256, 0, stream>>>(hin, W1l, bias, apb, bbuf);
        big_kernel<<<B_ * N_, 256, 0, stream>>>(rel, adj, WkcT, apb, bbuf,
                                                W2 + (size_t)l * D_ * D_, b2 + l * D_,
                                                hin, gamma, beta, hout);
    }
}